// Round 1
// baseline (657.632 us; speedup 1.0000x reference)
//
#include <hip/hip_runtime.h>

// CustomWeightedTensorProduct: Z=100000 rows, per row:
//   x1[64]  = s1_0[16] ++ s1_1[16][3]
//   x2[4]   = s2_0 ++ s2_1[3]
//   w[1280] = 5 segments of [u=16][wout=16]
//   out[64] = out0[16] ++ out1[wout=16][i=3]
// Memory-bound streaming kernel: one wave per row.

__global__ __launch_bounds__(256, 4) void ctp_kernel(
    const float* __restrict__ x1,
    const float* __restrict__ x2,
    const float* __restrict__ w,
    float* __restrict__ out,
    int Z)
{
    const int lane = threadIdx.x & 63;
    const int wid  = threadIdx.x >> 6;
    const int wavesPerBlock = blockDim.x >> 6;
    const int gwave  = blockIdx.x * wavesPerBlock + wid;
    const int nwaves = gridDim.x * wavesPerBlock;

    const int u = lane >> 2;   // u index handled by this lane (16 groups of 4 lanes)
    const int c = lane & 3;    // wout block: this lane's weights cover wout = 4c..4c+3

    // Scale factors folded into per-lane scalars.
    const float inv32 = 0.17677669529663687f;   // 1/sqrt(32)
    const float inv48 = 0.14433756729740643f;   // 1/sqrt(48)
    const float inv3  = 0.57735026918962576f;   // 1/sqrt(3)
    const float inv2  = 0.70710678118654752f;   // 1/sqrt(2)

    for (int row = gwave; row < Z; row += nwaves) {
        const float* x1r = x1 + (size_t)row * 64;
        const float4 x2v = *(const float4*)(x2 + (size_t)row * 4);
        const float s20   = x2v.x;
        const float s21_0 = x2v.y, s21_1 = x2v.z, s21_2 = x2v.w;

        // Broadcast-ish loads (4 lanes share each address; L1 hits; the row is
        // 256B and read once from HBM regardless).
        const float s10   = x1r[u];
        const float s11_0 = x1r[16 + 3*u + 0];
        const float s11_1 = x1r[16 + 3*u + 1];
        const float s11_2 = x1r[16 + 3*u + 2];

        // Coalesced weight loads: 5 x 1KiB per wave.
        const float4* wr = (const float4*)(w + (size_t)row * 1280);
        const float4 w0 = wr[lane];
        const float4 w1 = wr[ 64 + lane];
        const float4 w2 = wr[128 + lane];
        const float4 w3 = wr[192 + lane];
        const float4 w4 = wr[256 + lane];

        // Per-lane u-dependent scalars (scales folded in).
        const float ka  = s10 * s20 * inv32;
        const float kd  = (s11_0*s21_0 + s11_1*s21_1 + s11_2*s21_2) * (inv3 * inv32);
        const float kb0 = s10 * s21_0 * inv48;
        const float kb1 = s10 * s21_1 * inv48;
        const float kb2 = s10 * s21_2 * inv48;
        const float kc0 = s11_0 * s20 * inv48;
        const float kc1 = s11_1 * s20 * inv48;
        const float kc2 = s11_2 * s20 * inv48;
        const float sc  = inv2 * inv48;
        const float ke0 = (s11_1*s21_2 - s11_2*s21_1) * sc;
        const float ke1 = (s11_2*s21_0 - s11_0*s21_2) * sc;
        const float ke2 = (s11_0*s21_1 - s11_1*s21_0) * sc;

        const float w0a[4] = {w0.x, w0.y, w0.z, w0.w};
        const float w1a[4] = {w1.x, w1.y, w1.z, w1.w};
        const float w2a[4] = {w2.x, w2.y, w2.z, w2.w};
        const float w3a[4] = {w3.x, w3.y, w3.z, w3.w};
        const float w4a[4] = {w4.x, w4.y, w4.z, w4.w};

        float acc0[4];       // partial out0[4c+j]
        float acc1[4][3];    // partial out1[4c+j][i]
        #pragma unroll
        for (int j = 0; j < 4; ++j) {
            acc0[j] = w0a[j] * ka + w3a[j] * kd;
            acc1[j][0] = w1a[j] * kb0 + w2a[j] * kc0 + w4a[j] * ke0;
            acc1[j][1] = w1a[j] * kb1 + w2a[j] * kc1 + w4a[j] * ke1;
            acc1[j][2] = w1a[j] * kb2 + w2a[j] * kc2 + w4a[j] * ke2;
        }

        // Butterfly reduction over the 16 u-groups (lanes strided by 4):
        // xor masks 4,8,16,32. Afterwards every lane holds the full sums for
        // its wout block c.
        #pragma unroll
        for (int m = 4; m <= 32; m <<= 1) {
            #pragma unroll
            for (int j = 0; j < 4; ++j) {
                acc0[j]    += __shfl_xor(acc0[j],    m, 64);
                acc1[j][0] += __shfl_xor(acc1[j][0], m, 64);
                acc1[j][1] += __shfl_xor(acc1[j][1], m, 64);
                acc1[j][2] += __shfl_xor(acc1[j][2], m, 64);
            }
        }

        // Write 64 floats = 16 float4s, by lanes 0..15.
        float* outr = out + (size_t)row * 64;
        if (lane < 4) {
            // out0[4c .. 4c+3]
            *(float4*)(outr + 4*c) = make_float4(acc0[0], acc0[1], acc0[2], acc0[3]);
        } else if (lane < 16) {
            // out1 flat region: group c occupies floats [12c, 12c+12) after out0.
            const int t = (lane >> 2) - 1;  // 0..2: which float4 of the group
            float v0, v1, v2, v3;
            if (t == 0)      { v0 = acc1[0][0]; v1 = acc1[0][1]; v2 = acc1[0][2]; v3 = acc1[1][0]; }
            else if (t == 1) { v0 = acc1[1][1]; v1 = acc1[1][2]; v2 = acc1[2][0]; v3 = acc1[2][1]; }
            else             { v0 = acc1[2][2]; v1 = acc1[3][0]; v2 = acc1[3][1]; v3 = acc1[3][2]; }
            *(float4*)(outr + 16 + 12*c + 4*t) = make_float4(v0, v1, v2, v3);
        }
    }
}

extern "C" void kernel_launch(void* const* d_in, const int* in_sizes, int n_in,
                              void* d_out, int out_size, void* d_ws, size_t ws_size,
                              hipStream_t stream) {
    const float* x1 = (const float*)d_in[0];
    const float* x2 = (const float*)d_in[1];
    const float* w  = (const float*)d_in[2];
    float* out = (float*)d_out;

    const int Z = in_sizes[1] / 4;   // x2 is (Z,4)

    // Memory-bound streaming: cap grid, grid-stride the rows.
    // 2048 blocks x 256 threads = 8192 waves; ~12 rows per wave.
    const int blocks = 2048;
    hipLaunchKernelGGL(ctp_kernel, dim3(blocks), dim3(256), 0, stream,
                       x1, x2, w, out, Z);
}

// Round 2
// 649.665 us; speedup vs baseline: 1.0123x; 1.0123x over previous
//
#include <hip/hip_runtime.h>

// CustomWeightedTensorProduct: Z=100000 rows, per row:
//   x1[64]  = s1_0[16] ++ s1_1[16][3]
//   x2[4]   = s2_0 ++ s2_1[3]
//   w[1280] = 5 segments of [u=16][wout=16]
//   out[64] = out0[16] ++ out1[wout=16][i=3]
// Pure streaming, memory-bound. One wave per row; lane (u=lane>>2, c=lane&3)
// computes partials for outputs 4c..4c+3 (both out0 and out1) at its u, then a
// reduce-SCATTER butterfly (15 shuffles, not 64) leaves each lane with exactly
// one final output value -> single coalesced 64-lane store per row.

typedef float f32x4 __attribute__((ext_vector_type(4)));

__global__ __launch_bounds__(256, 4) void ctp_kernel(
    const float* __restrict__ x1,
    const float* __restrict__ x2,
    const float* __restrict__ w,
    float* __restrict__ out,
    int Z)
{
    const int lane = threadIdx.x & 63;
    const int wid  = threadIdx.x >> 6;
    const int gwave  = blockIdx.x * (blockDim.x >> 6) + wid;
    const int nwaves = gridDim.x * (blockDim.x >> 6);

    const int u = lane >> 2;   // u-group (16 of them, 4 lanes each)
    const int c = lane & 3;    // wout block: this lane's weights cover wout=4c..4c+3

    const float inv32 = 0.17677669529663687f;   // 1/sqrt(32)
    const float inv48 = 0.14433756729740643f;   // 1/sqrt(48)
    const float inv3  = 0.57735026918962576f;   // 1/sqrt(3)
    const float inv2  = 0.70710678118654752f;   // 1/sqrt(2)

    // After reduce-scatter, this lane holds final output index u of its c-group:
    //   u<4  -> out0[4c+u]            -> flat offset 4c+u
    //   u>=4 -> out1[4c+j][i], t=u-4, j=t/3, i=t%3 -> 16 + 12c + t = 12c+12+u
    const int off = (u < 4) ? (4*c + u) : (12*c + 12 + u);
    const int ub0 = u & 1, ub1 = (u >> 1) & 1, ub2 = (u >> 2) & 1, ub3 = (u >> 3) & 1;

    int row = gwave;
    if (row >= Z) return;

    // ---- prefetch row `row` ----
    f32x4 cw0, cw1, cw2, cw3, cw4, cx2;
    float cxa, cxb, cxc, cxd;
    {
        const f32x4* wr = (const f32x4*)(w + (size_t)row * 1280);
        cw0 = __builtin_nontemporal_load(wr + lane);
        cw1 = __builtin_nontemporal_load(wr + 64 + lane);
        cw2 = __builtin_nontemporal_load(wr + 128 + lane);
        cw3 = __builtin_nontemporal_load(wr + 192 + lane);
        cw4 = __builtin_nontemporal_load(wr + 256 + lane);
        const float* x1r = x1 + (size_t)row * 64;
        cxa = __builtin_nontemporal_load(x1r + u);
        cxb = __builtin_nontemporal_load(x1r + 16 + 3*u);
        cxc = __builtin_nontemporal_load(x1r + 17 + 3*u);
        cxd = __builtin_nontemporal_load(x1r + 18 + 3*u);
        cx2 = __builtin_nontemporal_load((const f32x4*)(x2 + (size_t)row * 4));
    }

    while (true) {
        const int nrow = row + nwaves;
        const bool have_next = (nrow < Z);

        // ---- issue next row's loads (hide HBM latency under compute) ----
        f32x4 nw0, nw1, nw2, nw3, nw4, nx2;
        float nxa, nxb, nxc, nxd;
        if (have_next) {
            const f32x4* wr = (const f32x4*)(w + (size_t)nrow * 1280);
            nw0 = __builtin_nontemporal_load(wr + lane);
            nw1 = __builtin_nontemporal_load(wr + 64 + lane);
            nw2 = __builtin_nontemporal_load(wr + 128 + lane);
            nw3 = __builtin_nontemporal_load(wr + 192 + lane);
            nw4 = __builtin_nontemporal_load(wr + 256 + lane);
            const float* x1r = x1 + (size_t)nrow * 64;
            nxa = __builtin_nontemporal_load(x1r + u);
            nxb = __builtin_nontemporal_load(x1r + 16 + 3*u);
            nxc = __builtin_nontemporal_load(x1r + 17 + 3*u);
            nxd = __builtin_nontemporal_load(x1r + 18 + 3*u);
            nx2 = __builtin_nontemporal_load((const f32x4*)(x2 + (size_t)nrow * 4));
        }

        // ---- compute current row ----
        const float s20 = cx2.x, s21_0 = cx2.y, s21_1 = cx2.z, s21_2 = cx2.w;
        const float s10 = cxa, s11_0 = cxb, s11_1 = cxc, s11_2 = cxd;

        const float ka  = s10 * s20 * inv32;
        const float kd  = (s11_0*s21_0 + s11_1*s21_1 + s11_2*s21_2) * (inv3 * inv32);
        const float kb0 = s10 * s21_0 * inv48;
        const float kb1 = s10 * s21_1 * inv48;
        const float kb2 = s10 * s21_2 * inv48;
        const float kc0 = s11_0 * s20 * inv48;
        const float kc1 = s11_1 * s20 * inv48;
        const float kc2 = s11_2 * s20 * inv48;
        const float sc  = inv2 * inv48;
        const float ke0 = (s11_1*s21_2 - s11_2*s21_1) * sc;
        const float ke1 = (s11_2*s21_0 - s11_0*s21_2) * sc;
        const float ke2 = (s11_0*s21_1 - s11_1*s21_0) * sc;

        // 16 partial values: v[0..3]=out0[4c+j], v[4+3j+i]=out1[4c+j][i]
        float v[16];
        #pragma unroll
        for (int j = 0; j < 4; ++j) {
            v[j]         = cw0[j]*ka  + cw3[j]*kd;
            v[4 + 3*j+0] = cw1[j]*kb0 + cw2[j]*kc0 + cw4[j]*ke0;
            v[4 + 3*j+1] = cw1[j]*kb1 + cw2[j]*kc1 + cw4[j]*ke1;
            v[4 + 3*j+2] = cw1[j]*kb2 + cw2[j]*kc2 + cw4[j]*ke2;
        }

        // ---- reduce-scatter butterfly over the 16 u-lanes (stride 4) ----
        // Round 0: xor 4, split on value-bit0 vs ub0
        float a[8];
        #pragma unroll
        for (int m = 0; m < 8; ++m) {
            const float keep = ub0 ? v[2*m+1] : v[2*m];
            const float send = ub0 ? v[2*m]   : v[2*m+1];
            a[m] = keep + __shfl_xor(send, 4, 64);
        }
        // Round 1: xor 8
        float b[4];
        #pragma unroll
        for (int m = 0; m < 4; ++m) {
            const float keep = ub1 ? a[2*m+1] : a[2*m];
            const float send = ub1 ? a[2*m]   : a[2*m+1];
            b[m] = keep + __shfl_xor(send, 8, 64);
        }
        // Round 2: xor 16
        float e[2];
        #pragma unroll
        for (int m = 0; m < 2; ++m) {
            const float keep = ub2 ? b[2*m+1] : b[2*m];
            const float send = ub2 ? b[2*m]   : b[2*m+1];
            e[m] = keep + __shfl_xor(send, 16, 64);
        }
        // Round 3: xor 32
        {
            const float keep = ub3 ? e[1] : e[0];
            const float send = ub3 ? e[0] : e[1];
            const float d = keep + __shfl_xor(send, 32, 64);
            // Every lane stores exactly one value; addresses are a permutation
            // of [row*64, row*64+64) -> fully coalesced.
            __builtin_nontemporal_store(d, out + (size_t)row * 64 + off);
        }

        if (!have_next) break;
        cw0 = nw0; cw1 = nw1; cw2 = nw2; cw3 = nw3; cw4 = nw4;
        cxa = nxa; cxb = nxb; cxc = nxc; cxd = nxd; cx2 = nx2;
        row = nrow;
    }
}

extern "C" void kernel_launch(void* const* d_in, const int* in_sizes, int n_in,
                              void* d_out, int out_size, void* d_ws, size_t ws_size,
                              hipStream_t stream) {
    const float* x1 = (const float*)d_in[0];
    const float* x2 = (const float*)d_in[1];
    const float* w  = (const float*)d_in[2];
    float* out = (float*)d_out;

    const int Z = in_sizes[1] / 4;   // x2 is (Z,4)

    // 2048 blocks x 4 waves = 8192 waves resident (32 waves/CU), grid-stride.
    hipLaunchKernelGGL(ctp_kernel, dim3(2048), dim3(256), 0, stream,
                       x1, x2, w, out, Z);
}